// Round 11
// baseline (1869.809 us; speedup 1.0000x reference)
//
#include <hip/hip_runtime.h>
#include <cmath>

// Problem constants
constexpr int cB  = 4096;
constexpr int cT  = 45;
constexpr int cD  = 128;
constexpr int cH  = 512;
constexpr int cG  = 2048;   // 4*H
constexpr int cTp = 9;
constexpr int cKE = 640;    // enc GEMM K: 128 (feat) + 512 (hidden)
constexpr int cKD = 1024;   // dec GEMM K: 512 (xenc) + 512 (hidden)

typedef __attribute__((ext_vector_type(8))) short short8;   // 8 bf16
typedef __attribute__((ext_vector_type(4))) float f32x4;

__device__ __forceinline__ short f2b(float f) {             // fp32 -> bf16 RNE
  unsigned int u = __float_as_uint(f);
  u += 0x7fff + ((u >> 16) & 1);
  return (short)(u >> 16);
}
__device__ __forceinline__ float b2f(short s) {
  return __uint_as_float(((unsigned int)(unsigned short)s) << 16);
}
__device__ __forceinline__ float dot4(float4 a, float4 b) {
  return a.x * b.x + a.y * b.y + a.z * b.z + a.w * b.w;
}

// Workspace layout (float offsets; bf16 buffers use n/2 float slots)
constexpr long ofFeatB = 0;                                    // B*9*128 bf16
constexpr long ofWencB = ofFeatB + (long)cB * cTp * 128 / 2;   // 2048*640 bf16 (gate-interleaved)
constexpr long ofBenc  = ofWencB + (long)cG * cKE / 2;         // 2048 f32 (interleaved)
constexpr long ofWdecB = ofBenc  + cG;                         // 2048*1024 bf16 (interleaved)
constexpr long ofBdec  = ofWdecB + (long)cG * cKD / 2;         // 2048 f32
constexpr long ofWy    = ofBdec  + cG;                         // 2048 f32 (interleaved y col)
constexpr long ofCenc  = ofWy    + cG;                         // B*512 f32
constexpr long ofH0enc = ofCenc  + (long)cB * cH;              // B*512 bf16 (ping)
constexpr long ofH1enc = ofH0enc + (long)cB * cH / 2;          // B*512 bf16 (pong)
constexpr long ofXencB = ofH1enc + (long)cB * cH / 2;          // B*9*512 bf16
constexpr long ofCdec  = ofXencB + (long)cB * cTp * cH / 2;    // B*512 f32
constexpr long ofH0dec = ofCdec  + (long)cB * cH;              // B*512 bf16
constexpr long ofH1dec = ofH0dec + (long)cB * cH / 2;          // B*512 bf16
constexpr long ofWqkv  = ofH1dec + (long)cB * cH / 2;          // 1536*512 bf16
constexpr long ofQkvB  = ofWqkv  + (long)3 * cH * cH / 2;      // B*1536 bf16
constexpr long ofZB    = ofQkvB  + (long)cB * 3 * cH / 2;      // B*B bf16 (z/beta)
constexpr long ofVT    = ofZB    + (long)cB * cB / 2;          // 512*B bf16
constexpr long ofSt    = ofVT    + (long)cH * cB / 2;          // B*512 f32
constexpr long wsFloats = ofSt   + (long)cB * cH;              // ~37M floats ~148 MB

// ---------------------------------------------------------------------------
// RCNN front-end, register-tiled (4 channels x 2 positions per thread) to cut
// LDS traffic ~3x (was LDS-BW-bound: ~1.7MB LDS reads/block x 16384 blocks
// = 28GB / 69TB/s = 405us measured). Strides padded for bank spread.
// ---------------------------------------------------------------------------
__global__ __launch_bounds__(256) void rcnn_kernel(
    const float* __restrict__ x,
    const float* __restrict__ w1, const float* __restrict__ b1,
    const float* __restrict__ w2, const float* __restrict__ b2,
    const float* __restrict__ w3, const float* __restrict__ b3,
    short* __restrict__ featB) {
  const int b = blockIdx.x;
  const int s = blockIdx.y;           // 0..3 -> stride s+1
  const int stride = s + 1;
  const int L  = (cT + stride - 1) / stride;  // 45,23,15,12
  const int L2 = L - 2;                       // 43,21,13,10
  const int Lp = L2 / 2;                      // 21,10, 6, 5
  const int L3 = Lp - 2;                      // 19, 8, 4, 3
  const int Lf = L3 / 2;                      //  9, 4, 2, 1
  const int pad = cTp - Lf;
  const int tid = threadIdx.x;

  __shared__ float smem[11628];
  float* xs  = smem;            // [45][132]  5940 (dead after conv1)
  float* w1s = smem + 5940;     // [16][132]  2112 (dead after conv1)
  float* w2r = smem + 8052;     // [96][20]   1920 (row=(c,kk), col=ci)
  float* h1t = smem + 9972;     // [45][20]    900
  float* p2t = smem + 10872;    // [21][36]    756
  float* w3r = smem;            // alias xs:  [96][36] 3456
  float* h3t = smem + 3456;     // alias xs:  [19][36]  684
  float* h2t = smem + 5940;     // alias w1s: [43][36] 1548

  // stage x, w1, w2
  for (int i = tid; i < L * 128; i += 256) {
    int l = i >> 7, d = i & 127;
    xs[l * 132 + d] = x[((long)b * cT + (long)l * stride) * cD + d];
  }
  for (int i = tid; i < 16 * 128; i += 256) {
    int c = i >> 7, d = i & 127;
    w1s[c * 132 + d] = w1[s * 2048 + i];
  }
  for (int i = tid; i < 32 * 48; i += 256) {
    int c = i / 48, r = i % 48, ci = r / 3, kk = r % 3;
    w2r[(c * 3 + kk) * 20 + ci] = w2[s * 1536 + i];
  }
  __syncthreads();

  // conv1: 4c x 2l per thread. h1t[l][c] = b1[c] + sum_d w1[c][d]*x[l][d]
  {
    const int c4 = tid & 3, lp = tid >> 2;
    const int Lh = (L + 1) >> 1;
    if (lp < Lh) {
      int l0 = 2 * lp, l1 = l0 + 1;
      bool has1 = l1 < L;
      int l1r = has1 ? l1 : l0;
      float a0[4], a1[4];
#pragma unroll
      for (int cc = 0; cc < 4; ++cc) { a0[cc] = b1[s * 16 + 4 * c4 + cc]; a1[cc] = a0[cc]; }
      const float4* x0 = (const float4*)&xs[l0 * 132];
      const float4* x1 = (const float4*)&xs[l1r * 132];
#pragma unroll 8
      for (int d4 = 0; d4 < 32; ++d4) {
        float4 xv0 = x0[d4], xv1 = x1[d4];
#pragma unroll
        for (int cc = 0; cc < 4; ++cc) {
          float4 wv = *(const float4*)&w1s[(4 * c4 + cc) * 132 + 4 * d4];
          a0[cc] += dot4(xv0, wv);
          a1[cc] += dot4(xv1, wv);
        }
      }
#pragma unroll
      for (int cc = 0; cc < 4; ++cc) {
        h1t[l0 * 20 + 4 * c4 + cc] = a0[cc];
        if (has1) h1t[l1 * 20 + 4 * c4 + cc] = a1[cc];
      }
    }
  }
  __syncthreads();

  // stage w3 into xs region (dead) while conv2 runs
  for (int i = tid; i < 32 * 96; i += 256) {
    int c = i / 96, r = i % 96, ci = r / 3, kk = r % 3;
    w3r[(c * 3 + kk) * 36 + ci] = w3[s * 3072 + i];
  }
  // conv2: 4c x 2l per thread
  {
    const int c8 = tid & 7, lp = tid >> 3;
    const int L2h = (L2 + 1) >> 1;
    if (lp < L2h) {
      int l0 = 2 * lp, l1 = l0 + 1;
      bool has1 = l1 < L2;
      float a0[4], a1[4];
#pragma unroll
      for (int cc = 0; cc < 4; ++cc) { a0[cc] = b2[s * 32 + 4 * c8 + cc]; a1[cc] = a0[cc]; }
#pragma unroll
      for (int kk = 0; kk < 3; ++kk) {
        float4 hA[4], hB4[4];
#pragma unroll
        for (int g = 0; g < 4; ++g) {
          hA[g] = *(const float4*)&h1t[(l0 + kk) * 20 + 4 * g];      // rows <= L-1: in bounds
          hB4[g] = *(const float4*)&h1t[(l0 + kk + 1) * 20 + 4 * g];
        }
#pragma unroll
        for (int cc = 0; cc < 4; ++cc) {
          const float4* wv = (const float4*)&w2r[((4 * c8 + cc) * 3 + kk) * 20];
          float s0 = 0, s1 = 0;
#pragma unroll
          for (int g = 0; g < 4; ++g) { s0 += dot4(hA[g], wv[g]); s1 += dot4(hB4[g], wv[g]); }
          a0[cc] += s0; a1[cc] += s1;
        }
      }
#pragma unroll
      for (int cc = 0; cc < 4; ++cc) {
        h2t[l0 * 36 + 4 * c8 + cc] = a0[cc];
        if (has1) h2t[l1 * 36 + 4 * c8 + cc] = a1[cc];
      }
    }
  }
  __syncthreads();

  // maxpool2 (vectorized float4)
  for (int i = tid; i < 8 * Lp; i += 256) {
    int l = i >> 3, g = i & 7;
    float4 u = *(const float4*)&h2t[(2 * l) * 36 + 4 * g];
    float4 v = *(const float4*)&h2t[(2 * l + 1) * 36 + 4 * g];
    float4 m; m.x = fmaxf(u.x, v.x); m.y = fmaxf(u.y, v.y);
    m.z = fmaxf(u.z, v.z); m.w = fmaxf(u.w, v.w);
    *(float4*)&p2t[l * 36 + 4 * g] = m;
  }
  __syncthreads();

  // conv3: 4c x 2l per thread
  {
    const int c8 = tid & 7, lp = tid >> 3;
    const int L3h = (L3 + 1) >> 1;
    if (lp < L3h) {
      int l0 = 2 * lp, l1 = l0 + 1;
      bool has1 = l1 < L3;
      float a0[4], a1[4];
#pragma unroll
      for (int cc = 0; cc < 4; ++cc) { a0[cc] = b3[s * 32 + 4 * c8 + cc]; a1[cc] = a0[cc]; }
#pragma unroll
      for (int kk = 0; kk < 3; ++kk) {
        float4 pA[8], pB8[8];
#pragma unroll
        for (int g = 0; g < 8; ++g) {
          pA[g] = *(const float4*)&p2t[(l0 + kk) * 36 + 4 * g];       // rows <= Lp-1: in bounds
          pB8[g] = *(const float4*)&p2t[(l0 + kk + 1) * 36 + 4 * g];
        }
#pragma unroll
        for (int cc = 0; cc < 4; ++cc) {
          const float4* wv = (const float4*)&w3r[((4 * c8 + cc) * 3 + kk) * 36];
          float s0 = 0, s1 = 0;
#pragma unroll
          for (int g = 0; g < 8; ++g) { s0 += dot4(pA[g], wv[g]); s1 += dot4(pB8[g], wv[g]); }
          a0[cc] += s0; a1[cc] += s1;
        }
      }
#pragma unroll
      for (int cc = 0; cc < 4; ++cc) {
        h3t[l0 * 36 + 4 * c8 + cc] = a0[cc];
        if (has1) h3t[l1 * 36 + 4 * c8 + cc] = a1[cc];
      }
    }
  }
  __syncthreads();

  // maxpool3 + left-pad + bf16 write
  for (int i = tid; i < 32 * cTp; i += 256) {
    int c = i / cTp, t = i % cTp;
    float v = 0.0f;
    if (t >= pad) {
      int l = t - pad;
      v = fmaxf(h3t[(2 * l) * 36 + c], h3t[(2 * l + 1) * 36 + c]);
    }
    featB[((long)b * cTp + t) * 128 + s * 32 + c] = f2b(v);
  }
}

// ---------------------------------------------------------------------------
// Weight prep with GATE INTERLEAVE: W row (4j+g) = orig row (g*512+j), so a
// 16-col MFMA fragment holds 4 complete hidden units (all 4 gates) -> LSTM
// pointwise can fuse into the GEMM epilogue. bias/wy interleaved likewise.
// ---------------------------------------------------------------------------
__global__ void prep_enc_w(const float* __restrict__ wih, const float* __restrict__ whh,
                           const float* __restrict__ bih, const float* __restrict__ bhh,
                           short* __restrict__ W, float* __restrict__ bias) {
  long i = (long)blockIdx.x * 256 + threadIdx.x;
  if (i < (long)cG * cKE) {
    int gp = (int)(i / cKE), k = (int)(i % cKE);
    int og = (gp & 3) * 512 + (gp >> 2);
    float v = (k < 128) ? wih[(long)og * 128 + k] : whh[(long)og * 512 + (k - 128)];
    W[i] = f2b(v);
  }
  if (i < cG) {
    int og = ((int)i & 3) * 512 + ((int)i >> 2);
    bias[i] = bih[og] + bhh[og];
  }
}

__global__ void prep_dec_w(const float* __restrict__ wih, const float* __restrict__ whh,
                           const float* __restrict__ bih, const float* __restrict__ bhh,
                           short* __restrict__ W, float* __restrict__ bias,
                           float* __restrict__ wy) {
  long i = (long)blockIdx.x * 256 + threadIdx.x;
  if (i < (long)cG * cKD) {
    int gp = (int)(i / cKD), k = (int)(i % cKD);
    int og = (gp & 3) * 512 + (gp >> 2);
    float v = (k < 512) ? wih[(long)og * 513 + k] : whh[(long)og * 512 + (k - 512)];
    W[i] = f2b(v);
  }
  if (i < cG) {
    int og = ((int)i & 3) * 512 + ((int)i >> 2);
    bias[i] = bih[og] + bhh[og];
    wy[i] = wih[(long)og * 513 + 512];
  }
}

__global__ void prep_qkv_w(const float* __restrict__ wq, const float* __restrict__ wk,
                           const float* __restrict__ wv, short* __restrict__ W) {
  long i = (long)blockIdx.x * 256 + threadIdx.x;
  if (i >= (long)3 * cH * cH) return;
  int r = (int)(i / cH), k = (int)(i % cH);
  float v = (r < 512) ? wq[(long)r * cH + k]
          : (r < 1024) ? wk[(long)(r - 512) * cH + k]
                       : wv[(long)(r - 1024) * cH + k];
  W[i] = f2b(v);
}

// ---------------------------------------------------------------------------
// bf16 MFMA NT GEMM (m97 staging: global_load_lds width=16, linear LDS).
// Dual-source A (k<K1 from A1, else A2). 128x128 tile, 4 waves, 4x4 frags of
// v_mfma_f32_16x16x32_bf16. C/D map (m89/m91): col=lane&15, row=(lane>>4)*4+reg.
// MODE 0: plain epilogue (alpha, optional bias, f32 C and/or bf16 Cb out).
// MODE 1: fused LSTM epilogue. N=2048 gate-interleaved. Per 16x16 frag: stage
//   to wave-private LDS (stride 16), re-read f32x4 per lane = {i,f,g,o} of one
//   hidden unit; apply bias (+ y*wy), sigmoid/tanh, update c, write bf16 h/x.
// ---------------------------------------------------------------------------
template <int MODE>
__global__ __launch_bounds__(256) void gemm_bf16_nt(
    const short* __restrict__ A1, int lda1, int K1,
    const short* __restrict__ A2, int lda2,
    const short* __restrict__ W, int ldw,
    const float* __restrict__ bias,
    float* __restrict__ C, short* __restrict__ Cb, int ldc,
    int K, float alpha,
    float* __restrict__ cst, short* __restrict__ hB, short* __restrict__ xB, int t,
    const float* __restrict__ y, int yidx, const float* __restrict__ wy) {
  __shared__ short lsA[128 * 32];
  __shared__ short lsB[128 * 32];
  __shared__ float scr[4 * 256];   // wave-private frag scratch (MODE 1)
  const int tid  = threadIdx.x;
  const int lane = tid & 63;
  const int wave = tid >> 6;
  const int wr = wave >> 1, wc = wave & 1;
  const long m0 = (long)blockIdx.x * 128;
  const long n0 = (long)blockIdx.y * 128;

  f32x4 acc[4][4];
#pragma unroll
  for (int i = 0; i < 4; ++i)
#pragma unroll
    for (int j = 0; j < 4; ++j) acc[i][j] = (f32x4)0.0f;

  const int segrow = lane >> 2;        // 0..15
  const int chunk  = (lane & 3) * 8;   // bf16 elem offset within row
  const int rbase  = lane & 15;
  const int kk     = (lane >> 4) * 8;

  for (int k0 = 0; k0 < K; k0 += 32) {
    const short* Ab; long alda; int acol;
    if (k0 < K1) { Ab = A1; alda = lda1; acol = k0; }
    else         { Ab = A2; alda = lda2; acol = k0 - K1; }
    __syncthreads();
#pragma unroll
    for (int cs = 0; cs < 2; ++cs) {
      int r = wave * 32 + cs * 16 + segrow;
      const short* ga = Ab + (m0 + r) * alda + acol + chunk;
      __builtin_amdgcn_global_load_lds(
          (const __attribute__((address_space(1))) void*)ga,
          (__attribute__((address_space(3))) void*)&lsA[(wave * 32 + cs * 16) * 32],
          16, 0, 0);
      const short* gw = W + (n0 + r) * (long)ldw + k0 + chunk;
      __builtin_amdgcn_global_load_lds(
          (const __attribute__((address_space(1))) void*)gw,
          (__attribute__((address_space(3))) void*)&lsB[(wave * 32 + cs * 16) * 32],
          16, 0, 0);
    }
    __syncthreads();

    short8 af[4], bf4[4];
#pragma unroll
    for (int i = 0; i < 4; ++i)
      af[i] = *(const short8*)&lsA[(wr * 64 + i * 16 + rbase) * 32 + kk];
#pragma unroll
    for (int j = 0; j < 4; ++j)
      bf4[j] = *(const short8*)&lsB[(wc * 64 + j * 16 + rbase) * 32 + kk];
#pragma unroll
    for (int i = 0; i < 4; ++i)
#pragma unroll
      for (int j = 0; j < 4; ++j)
        acc[i][j] = __builtin_amdgcn_mfma_f32_16x16x32_bf16(af[i], bf4[j], acc[i][j], 0, 0, 0);
  }

  if constexpr (MODE == 0) {
#pragma unroll
    for (int i = 0; i < 4; ++i) {
#pragma unroll
      for (int j = 0; j < 4; ++j) {
        long ncol = n0 + wc * 64 + j * 16 + (lane & 15);
        float bv = bias ? bias[ncol] : 0.0f;
#pragma unroll
        for (int r = 0; r < 4; ++r) {
          long mrow = m0 + wr * 64 + i * 16 + (lane >> 4) * 4 + r;
          float v = acc[i][j][r] * alpha + bv;
          if (C)  C[mrow * ldc + ncol] = v;
          if (Cb) Cb[mrow * ldc + ncol] = f2b(v);
        }
      }
    }
  } else {
    // Fused LSTM epilogue. Writer: lane holds col c0=lane&15, rows r0+0..3.
    // Reader: lane owns (row=lane>>2, hidden-sub jj=lane&3) -> f32x4 gates.
    float* scrw = scr + wave * 256;
    const int c0 = lane & 15;
    const int r0 = (lane >> 4) * 4;
    const int rrow = lane >> 2;
    const int jj = lane & 3;
#pragma unroll
    for (int i = 0; i < 4; ++i) {
      long b = m0 + wr * 64 + i * 16 + rrow;
      float yb = y ? y[b * cT + yidx] : 0.0f;
#pragma unroll
      for (int jf = 0; jf < 4; ++jf) {
#pragma unroll
        for (int rr = 0; rr < 4; ++rr) scrw[(r0 + rr) * 16 + c0] = acc[i][jf][rr];
        long nbase = n0 + wc * 64 + jf * 16;       // divisible by 4
        long j = (nbase >> 2) + jj;                // global hidden unit
        f32x4 g4 = *(f32x4*)&scrw[rrow * 16 + jj * 4];
        f32x4 b4 = *(const f32x4*)&bias[4 * j];
        float ig = g4[0] + b4[0], fg = g4[1] + b4[1];
        float gg = g4[2] + b4[2], og = g4[3] + b4[3];
        if (y) {
          f32x4 w4 = *(const f32x4*)&wy[4 * j];
          ig += yb * w4[0]; fg += yb * w4[1]; gg += yb * w4[2]; og += yb * w4[3];
        }
        float si = 1.0f / (1.0f + expf(-ig));
        float sf = 1.0f / (1.0f + expf(-fg));
        float so = 1.0f / (1.0f + expf(-og));
        long idx = b * cH + j;
        float cc = sf * cst[idx] + si * tanhf(gg);
        float hh = so * tanhf(cc);
        cst[idx] = cc;
        short hb = f2b(hh);
        hB[idx] = hb;
        if (xB) xB[(b * cTp + t) * cH + j] = hb;
      }
    }
  }
}

// ---------------------------------------------------------------------------
// Row softmax over bf16 z (B x B), in place (z -> beta).
// ---------------------------------------------------------------------------
__global__ __launch_bounds__(256) void softmax_b(short* __restrict__ zb) {
  const int row = blockIdx.x;
  short* zr = zb + (long)row * cB;
  const int tid = threadIdx.x;
  __shared__ float red[4];

  float e[16];
  float mx = -1e30f;
#pragma unroll
  for (int idx = 0; idx < 16; ++idx) {
    float v = b2f(zr[tid + idx * 256]);
    e[idx] = v;
    mx = fmaxf(mx, v);
  }
  for (int off = 32; off; off >>= 1) mx = fmaxf(mx, __shfl_xor(mx, off));
  if ((tid & 63) == 0) red[tid >> 6] = mx;
  __syncthreads();
  mx = fmaxf(fmaxf(red[0], red[1]), fmaxf(red[2], red[3]));
  __syncthreads();

  float sum = 0.0f;
#pragma unroll
  for (int idx = 0; idx < 16; ++idx) {
    float ev = expf(e[idx] - mx);
    e[idx] = ev;
    sum += ev;
  }
  for (int off = 32; off; off >>= 1) sum += __shfl_xor(sum, off);
  if ((tid & 63) == 0) red[tid >> 6] = sum;
  __syncthreads();
  sum = red[0] + red[1] + red[2] + red[3];
  float inv = 1.0f / sum;
#pragma unroll
  for (int idx = 0; idx < 16; ++idx) zr[tid + idx * 256] = f2b(e[idx] * inv);
}

// ---------------------------------------------------------------------------
// Transpose bf16 v (B x cH, row stride ldv) -> vT (cH x B)
// ---------------------------------------------------------------------------
__global__ __launch_bounds__(256) void transpose_v16(const short* __restrict__ v, int ldv,
                                                     short* __restrict__ vT) {
  __shared__ short tile[32][33];
  const int bx = blockIdx.x;  // along B/32
  const int by = blockIdx.y;  // along 512/32
  const int tx = threadIdx.x & 31, ty = threadIdx.x >> 5;  // 32x8
#pragma unroll
  for (int i = 0; i < 4; ++i)
    tile[ty + i * 8][tx] = v[(long)(bx * 32 + ty + i * 8) * ldv + by * 32 + tx];
  __syncthreads();
#pragma unroll
  for (int i = 0; i < 4; ++i)
    vT[(long)(by * 32 + ty + i * 8) * cB + bx * 32 + tx] = tile[tx][ty + i * 8];
}

// ---------------------------------------------------------------------------
// Final: out[b] = sigmoid(dot(st[b], ln_w) + ln_b). One wave per row.
// ---------------------------------------------------------------------------
__global__ __launch_bounds__(256) void final_kernel(const float* __restrict__ st,
                                                    const float* __restrict__ lnw,
                                                    const float* __restrict__ lnb,
                                                    float* __restrict__ out) {
  const int wave = threadIdx.x >> 6, lane = threadIdx.x & 63;
  const int b = blockIdx.x * 4 + wave;
  const float* sr = st + (long)b * cH;
  float acc = 0.0f;
  for (int j = lane; j < cH; j += 64) acc += sr[j] * lnw[j];
  for (int off = 32; off; off >>= 1) acc += __shfl_down(acc, off);
  if (lane == 0) out[b] = 1.0f / (1.0f + expf(-(acc + lnb[0])));
}

// ---------------------------------------------------------------------------
extern "C" void kernel_launch(void* const* d_in, const int* in_sizes, int n_in,
                              void* d_out, int out_size, void* d_ws, size_t ws_size,
                              hipStream_t stream) {
  const float* x       = (const float*)d_in[0];
  const float* y       = (const float*)d_in[1];
  const float* rcnn_w1 = (const float*)d_in[2];
  const float* rcnn_b1 = (const float*)d_in[3];
  const float* rcnn_w2 = (const float*)d_in[4];
  const float* rcnn_b2 = (const float*)d_in[5];
  const float* rcnn_w3 = (const float*)d_in[6];
  const float* rcnn_b3 = (const float*)d_in[7];
  const float* enc_wih = (const float*)d_in[8];
  const float* enc_whh = (const float*)d_in[9];
  const float* enc_bih = (const float*)d_in[10];
  const float* enc_bhh = (const float*)d_in[11];
  const float* dec_wih = (const float*)d_in[12];
  const float* dec_whh = (const float*)d_in[13];
  const float* dec_bih = (const float*)d_in[14];
  const float* dec_bhh = (const float*)d_in[15];
  const float* wq      = (const float*)d_in[16];
  const float* wk      = (const float*)d_in[17];
  const float* wv      = (const float*)d_in[18];
  const float* ln_w    = (const float*)d_in[19];
  const float* ln_b    = (const float*)d_in[20];
  float* out = (float*)d_out;

  if (ws_size < (size_t)wsFloats * sizeof(float)) return;  // ~148 MB scratch

  float* ws    = (float*)d_ws;
  short* featB = (short*)(ws + ofFeatB);
  short* WencB = (short*)(ws + ofWencB);
  float* benc  = ws + ofBenc;
  short* WdecB = (short*)(ws + ofWdecB);
  float* bdec  = ws + ofBdec;
  float* wyI   = ws + ofWy;
  float* cenc  = ws + ofCenc;
  short* hEnc[2] = { (short*)(ws + ofH0enc), (short*)(ws + ofH1enc) };
  short* xencB = (short*)(ws + ofXencB);
  float* cdec  = ws + ofCdec;
  short* hDec[2] = { (short*)(ws + ofH0dec), (short*)(ws + ofH1dec) };
  short* Wqkv  = (short*)(ws + ofWqkv);
  short* qkvB  = (short*)(ws + ofQkvB);
  short* zB    = (short*)(ws + ofZB);
  short* vT    = (short*)(ws + ofVT);
  float* st    = ws + ofSt;

  // 1. RCNN features (bf16 out)
  rcnn_kernel<<<dim3(cB, 4), 256, 0, stream>>>(x, rcnn_w1, rcnn_b1, rcnn_w2, rcnn_b2,
                                               rcnn_w3, rcnn_b3, featB);

  // 2. Weight prep (gate-interleaved for LSTM; concat for qkv)
  prep_enc_w<<<((long)cG * cKE + 255) / 256, 256, 0, stream>>>(enc_wih, enc_whh, enc_bih,
                                                               enc_bhh, WencB, benc);
  prep_dec_w<<<((long)cG * cKD + 255) / 256, 256, 0, stream>>>(dec_wih, dec_whh, dec_bih,
                                                               dec_bhh, WdecB, bdec, wyI);
  prep_qkv_w<<<((long)3 * cH * cH + 255) / 256, 256, 0, stream>>>(wq, wk, wv, Wqkv);

  // 3. Encoder LSTM: GEMM with fused pointwise epilogue; h ping-pong
  hipMemsetAsync(cenc, 0, (size_t)cB * cH * sizeof(float), stream);
  hipMemsetAsync(hEnc[0], 0, (size_t)cB * cH * sizeof(short), stream);
  for (int t = 0; t < cTp; ++t) {
    gemm_bf16_nt<1><<<dim3(cB / 128, cG / 128), 256, 0, stream>>>(
        featB + t * 128, cTp * 128, 128, hEnc[t & 1], cH,
        WencB, cKE, benc, nullptr, nullptr, 0, cKE, 1.0f,
        cenc, hEnc[(t + 1) & 1], xencB, t, nullptr, 0, nullptr);
  }

  // 4. Decoder LSTM (y rank-1 folded into epilogue)
  hipMemsetAsync(cdec, 0, (size_t)cB * cH * sizeof(float), stream);
  hipMemsetAsync(hDec[0], 0, (size_t)cB * cH * sizeof(short), stream);
  for (int t = 0; t < cTp; ++t) {
    int yidx = 4 + 5 * t;  // idx = [4,9,...,44]
    gemm_bf16_nt<1><<<dim3(cB / 128, cG / 128), 256, 0, stream>>>(
        xencB + t * cH, cTp * cH, 512, hDec[t & 1], cH,
        WdecB, cKD, bdec, nullptr, nullptr, 0, cKD, 1.0f,
        cdec, hDec[(t + 1) & 1], nullptr, t, y, yidx, wyI);
  }
  short* hd = hDec[cTp & 1];   // final decoder hidden (bf16)

  // 5. q,k,v in one GEMM (N=1536)
  gemm_bf16_nt<0><<<dim3(cB / 128, 3 * cH / 128), 256, 0, stream>>>(
      hd, cH, cH, nullptr, 0, Wqkv, cH, nullptr,
      nullptr, qkvB, 3 * cH, cH, 1.0f,
      nullptr, nullptr, nullptr, 0, nullptr, 0, nullptr);

  // 6. z = q@k^T / sqrt(H)
  const float alpha = 1.0f / sqrtf((float)cH);
  gemm_bf16_nt<0><<<dim3(cB / 128, cB / 128), 256, 0, stream>>>(
      qkvB, 3 * cH, cH, nullptr, 0, qkvB + cH, 3 * cH, nullptr,
      nullptr, zB, cB, cH, alpha,
      nullptr, nullptr, nullptr, 0, nullptr, 0, nullptr);

  // 7. softmax rows in place (z -> beta)
  softmax_b<<<cB, 256, 0, stream>>>(zB);

  // 8. st = beta @ v (via v^T)
  transpose_v16<<<dim3(cB / 32, cH / 32), 256, 0, stream>>>(qkvB + 2 * cH, 3 * cH, vT);
  gemm_bf16_nt<0><<<dim3(cB / 128, cH / 128), 256, 0, stream>>>(
      zB, cB, cB, nullptr, 0, vT, cB, nullptr,
      st, nullptr, cH, cB, 1.0f,
      nullptr, nullptr, nullptr, 0, nullptr, 0, nullptr);

  // 9. final sigmoid head
  final_kernel<<<cB / 4, 256, 0, stream>>>(st, ln_w, ln_b, out);
}

// Round 12
// 1261.072 us; speedup vs baseline: 1.4827x; 1.4827x over previous
//
#include <hip/hip_runtime.h>
#include <cmath>

// Problem constants
constexpr int cB  = 4096;
constexpr int cT  = 45;
constexpr int cD  = 128;
constexpr int cH  = 512;
constexpr int cG  = 2048;   // 4*H
constexpr int cTp = 9;
constexpr int cKE = 640;    // enc GEMM K: 128 (feat) + 512 (hidden)
constexpr int cKD = 1024;   // dec GEMM K: 512 (xenc) + 512 (hidden)

typedef __attribute__((ext_vector_type(8))) short short8;   // 8 bf16
typedef __attribute__((ext_vector_type(4))) float f32x4;

__device__ __forceinline__ short f2b(float f) {             // fp32 -> bf16 RNE
  unsigned int u = __float_as_uint(f);
  u += 0x7fff + ((u >> 16) & 1);
  return (short)(u >> 16);
}
__device__ __forceinline__ float b2f(short s) {
  return __uint_as_float(((unsigned int)(unsigned short)s) << 16);
}

// Workspace layout (float offsets; bf16 buffers use n/2 float slots)
constexpr long ofFeatB = 0;                                    // B*9*128 bf16
constexpr long ofWencB = ofFeatB + (long)cB * cTp * 128 / 2;   // 2048*640 bf16 (gate-interleaved)
constexpr long ofBenc  = ofWencB + (long)cG * cKE / 2;         // 2048 f32 (interleaved)
constexpr long ofWdecB = ofBenc  + cG;                         // 2048*1024 bf16 (interleaved)
constexpr long ofBdec  = ofWdecB + (long)cG * cKD / 2;         // 2048 f32
constexpr long ofWy    = ofBdec  + cG;                         // 2048 f32 (interleaved y col)
constexpr long ofCenc  = ofWy    + cG;                         // B*512 f32
constexpr long ofH0enc = ofCenc  + (long)cB * cH;              // B*512 bf16 (ping)
constexpr long ofH1enc = ofH0enc + (long)cB * cH / 2;          // B*512 bf16 (pong)
constexpr long ofXencB = ofH1enc + (long)cB * cH / 2;          // B*9*512 bf16
constexpr long ofCdec  = ofXencB + (long)cB * cTp * cH / 2;    // B*512 f32
constexpr long ofH0dec = ofCdec  + (long)cB * cH;              // B*512 bf16
constexpr long ofH1dec = ofH0dec + (long)cB * cH / 2;          // B*512 bf16
constexpr long ofWqkv  = ofH1dec + (long)cB * cH / 2;          // 1536*512 bf16
constexpr long ofQkvB  = ofWqkv  + (long)3 * cH * cH / 2;      // B*1536 bf16
constexpr long ofZB    = ofQkvB  + (long)cB * 3 * cH / 2;      // B*B bf16 (z/beta)
constexpr long ofVT    = ofZB    + (long)cB * cB / 2;          // 512*B bf16
constexpr long ofSt    = ofVT    + (long)cH * cB / 2;          // B*512 f32
constexpr long wsFloats = ofSt   + (long)cB * cH;              // ~37M floats ~148 MB

// ---------------------------------------------------------------------------
// RCNN front-end: round-10 all-lanes-active body at 512 threads/block.
// 45KB LDS -> 3 blocks/CU -> 24 waves/CU (was ~8-12 at 256 threads): more TLP
// to hide LDS latency. xs stride 132 kills the stride-128 conflict.
// Emits bf16 feat directly (GEMM A operand).
// ---------------------------------------------------------------------------
__global__ __launch_bounds__(512) void rcnn_kernel(
    const float* __restrict__ x,
    const float* __restrict__ w1, const float* __restrict__ b1,
    const float* __restrict__ w2, const float* __restrict__ b2,
    const float* __restrict__ w3, const float* __restrict__ b3,
    short* __restrict__ featB) {
  const int b = blockIdx.x;
  const int s = blockIdx.y;           // 0..3 -> stride s+1
  const int stride = s + 1;
  const int L  = (cT + stride - 1) / stride;  // 45,23,15,12
  const int L2 = L - 2;                       // 43,21,13,10
  const int Lp = L2 / 2;                      // 21,10, 6, 5
  const int L3 = Lp - 2;                      // 19, 8, 4, 3
  const int Lf = L3 / 2;                      //  9, 4, 2, 1
  const int pad = cTp - Lf;
  const int tid = threadIdx.x;

  // one shared pool with aliasing
  __shared__ float smem[11180];
  float* xs  = smem;            // [45][132]  5940  (dead after conv1)
  float* w1s = smem + 5940;     // [16][128]  2048  (dead after conv1)
  float* w2r = smem + 7988;     // [32][3][16] 1536
  float* h1t = smem + 9524;     // [45][20]    900
  float* p2t = smem + 10424;    // [21][36]    756
  float* w3r = smem;            // alias xs: [32][3][32] 3072
  float* h3t = smem + 3072;     // alias xs: [19][36]     684
  float* h2t = smem + 5940;     // alias w1s: [43][36]   1548

  // stage inputs
  for (int i = tid; i < L * 128; i += 512) {
    int l = i >> 7, d = i & 127;
    xs[l * 132 + d] = x[((long)b * cT + (long)l * stride) * cD + d];
  }
  for (int i = tid; i < 16 * 128; i += 512) w1s[i] = w1[s * 2048 + i];
  for (int i = tid; i < 32 * 48; i += 512) {
    int c = i / 48, r = i % 48, ci = r / 3, kk = r % 3;
    w2r[(c * 3 + kk) * 16 + ci] = w2[s * 1536 + i];
  }
  __syncthreads();

  // conv1: h1t[l][c] = b1[c] + sum_d w1[c][d]*xs[l][d]   (float4 over d)
  for (int i = tid; i < 16 * L; i += 512) {
    int c = i / L, l = i % L;
    const float4* xr = (const float4*)&xs[l * 132];
    const float4* wr = (const float4*)&w1s[c * 128];
    float acc = b1[s * 16 + c];
#pragma unroll
    for (int d4 = 0; d4 < 32; ++d4) {
      float4 xv = xr[d4], wv = wr[d4];
      acc += xv.x * wv.x + xv.y * wv.y + xv.z * wv.z + xv.w * wv.w;
    }
    h1t[l * 20 + c] = acc;
  }
  __syncthreads();

  // load w3 rearranged into xs region (xs dead) ; conv2 in parallel
  for (int i = tid; i < 32 * 96; i += 512) {
    int c = i / 96, r = i % 96, ci = r / 3, kk = r % 3;
    w3r[(c * 3 + kk) * 32 + ci] = w3[s * 3072 + i];
  }
  // conv2: h2t[l][c] = b2[c] + sum_{ci,kk} w2[c][ci][kk]*h1t[l+kk][ci]
  for (int i = tid; i < 32 * L2; i += 512) {
    int c = i / L2, l = i % L2;
    float acc = b2[s * 32 + c];
#pragma unroll
    for (int kk = 0; kk < 3; ++kk) {
      const float4* hp = (const float4*)&h1t[(l + kk) * 20];
      const float4* wp = (const float4*)&w2r[(c * 3 + kk) * 16];
#pragma unroll
      for (int g = 0; g < 4; ++g) {
        float4 hv = hp[g], wv = wp[g];
        acc += hv.x * wv.x + hv.y * wv.y + hv.z * wv.z + hv.w * wv.w;
      }
    }
    h2t[l * 36 + c] = acc;
  }
  __syncthreads();

  // maxpool2: p2t[l][c]
  for (int i = tid; i < 32 * Lp; i += 512) {
    int l = i >> 5, c = i & 31;
    p2t[l * 36 + c] = fmaxf(h2t[(2 * l) * 36 + c], h2t[(2 * l + 1) * 36 + c]);
  }
  __syncthreads();

  // conv3: h3t[l][c]
  for (int i = tid; i < 32 * L3; i += 512) {
    int c = i / L3, l = i % L3;
    float acc = b3[s * 32 + c];
#pragma unroll
    for (int kk = 0; kk < 3; ++kk) {
      const float4* pp = (const float4*)&p2t[(l + kk) * 36];
      const float4* wp = (const float4*)&w3r[(c * 3 + kk) * 32];
#pragma unroll
      for (int g = 0; g < 8; ++g) {
        float4 pv = pp[g], wv = wp[g];
        acc += pv.x * wv.x + pv.y * wv.y + pv.z * wv.z + pv.w * wv.w;
      }
    }
    h3t[l * 36 + c] = acc;
  }
  __syncthreads();

  // maxpool3 + left-pad + bf16 write
  for (int i = tid; i < 32 * cTp; i += 512) {
    int c = i / cTp, t = i % cTp;
    float v = 0.0f;
    if (t >= pad) {
      int l = t - pad;
      v = fmaxf(h3t[(2 * l) * 36 + c], h3t[(2 * l + 1) * 36 + c]);
    }
    featB[((long)b * cTp + t) * 128 + s * 32 + c] = f2b(v);
  }
}

// ---------------------------------------------------------------------------
// Weight prep with GATE INTERLEAVE: W row (4j+g) = orig row (g*512+j), so a
// 16-col MFMA fragment holds 4 complete hidden units (all 4 gates) -> LSTM
// pointwise can fuse into the GEMM epilogue. bias/wy interleaved likewise.
// ---------------------------------------------------------------------------
__global__ void prep_enc_w(const float* __restrict__ wih, const float* __restrict__ whh,
                           const float* __restrict__ bih, const float* __restrict__ bhh,
                           short* __restrict__ W, float* __restrict__ bias) {
  long i = (long)blockIdx.x * 256 + threadIdx.x;
  if (i < (long)cG * cKE) {
    int gp = (int)(i / cKE), k = (int)(i % cKE);
    int og = (gp & 3) * 512 + (gp >> 2);
    float v = (k < 128) ? wih[(long)og * 128 + k] : whh[(long)og * 512 + (k - 128)];
    W[i] = f2b(v);
  }
  if (i < cG) {
    int og = ((int)i & 3) * 512 + ((int)i >> 2);
    bias[i] = bih[og] + bhh[og];
  }
}

__global__ void prep_dec_w(const float* __restrict__ wih, const float* __restrict__ whh,
                           const float* __restrict__ bih, const float* __restrict__ bhh,
                           short* __restrict__ W, float* __restrict__ bias,
                           float* __restrict__ wy) {
  long i = (long)blockIdx.x * 256 + threadIdx.x;
  if (i < (long)cG * cKD) {
    int gp = (int)(i / cKD), k = (int)(i % cKD);
    int og = (gp & 3) * 512 + (gp >> 2);
    float v = (k < 512) ? wih[(long)og * 513 + k] : whh[(long)og * 512 + (k - 512)];
    W[i] = f2b(v);
  }
  if (i < cG) {
    int og = ((int)i & 3) * 512 + ((int)i >> 2);
    bias[i] = bih[og] + bhh[og];
    wy[i] = wih[(long)og * 513 + 512];
  }
}

__global__ void prep_qkv_w(const float* __restrict__ wq, const float* __restrict__ wk,
                           const float* __restrict__ wv, short* __restrict__ W) {
  long i = (long)blockIdx.x * 256 + threadIdx.x;
  if (i >= (long)3 * cH * cH) return;
  int r = (int)(i / cH), k = (int)(i % cH);
  float v = (r < 512) ? wq[(long)r * cH + k]
          : (r < 1024) ? wk[(long)(r - 512) * cH + k]
                       : wv[(long)(r - 1024) * cH + k];
  W[i] = f2b(v);
}

// ---------------------------------------------------------------------------
// bf16 MFMA NT GEMM (m97 staging: global_load_lds width=16, linear LDS).
// Dual-source A (k<K1 from A1, else A2). 128x128 tile, 4 waves, 4x4 frags of
// v_mfma_f32_16x16x32_bf16. C/D map (m89/m91): col=lane&15, row=(lane>>4)*4+reg.
// MODE 0: plain epilogue (alpha, optional bias, f32 C and/or bf16 Cb out).
// MODE 1: fused LSTM epilogue. N=2048 gate-interleaved. Per 16x16 frag: stage
//   to wave-private LDS (stride 16), re-read f32x4 per lane = {i,f,g,o} of one
//   hidden unit; apply bias (+ y*wy), sigmoid/tanh, update c, write bf16 h/x.
// ---------------------------------------------------------------------------
template <int MODE>
__global__ __launch_bounds__(256) void gemm_bf16_nt(
    const short* __restrict__ A1, int lda1, int K1,
    const short* __restrict__ A2, int lda2,
    const short* __restrict__ W, int ldw,
    const float* __restrict__ bias,
    float* __restrict__ C, short* __restrict__ Cb, int ldc,
    int K, float alpha,
    float* __restrict__ cst, short* __restrict__ hB, short* __restrict__ xB, int t,
    const float* __restrict__ y, int yidx, const float* __restrict__ wy) {
  __shared__ short lsA[128 * 32];
  __shared__ short lsB[128 * 32];
  __shared__ float scr[4 * 256];   // wave-private frag scratch (MODE 1)
  const int tid  = threadIdx.x;
  const int lane = tid & 63;
  const int wave = tid >> 6;
  const int wr = wave >> 1, wc = wave & 1;
  const long m0 = (long)blockIdx.x * 128;
  const long n0 = (long)blockIdx.y * 128;

  f32x4 acc[4][4];
#pragma unroll
  for (int i = 0; i < 4; ++i)
#pragma unroll
    for (int j = 0; j < 4; ++j) acc[i][j] = (f32x4)0.0f;

  const int segrow = lane >> 2;        // 0..15
  const int chunk  = (lane & 3) * 8;   // bf16 elem offset within row
  const int rbase  = lane & 15;
  const int kk     = (lane >> 4) * 8;

  for (int k0 = 0; k0 < K; k0 += 32) {
    const short* Ab; long alda; int acol;
    if (k0 < K1) { Ab = A1; alda = lda1; acol = k0; }
    else         { Ab = A2; alda = lda2; acol = k0 - K1; }
    __syncthreads();
#pragma unroll
    for (int cs = 0; cs < 2; ++cs) {
      int r = wave * 32 + cs * 16 + segrow;
      const short* ga = Ab + (m0 + r) * alda + acol + chunk;
      __builtin_amdgcn_global_load_lds(
          (const __attribute__((address_space(1))) void*)ga,
          (__attribute__((address_space(3))) void*)&lsA[(wave * 32 + cs * 16) * 32],
          16, 0, 0);
      const short* gw = W + (n0 + r) * (long)ldw + k0 + chunk;
      __builtin_amdgcn_global_load_lds(
          (const __attribute__((address_space(1))) void*)gw,
          (__attribute__((address_space(3))) void*)&lsB[(wave * 32 + cs * 16) * 32],
          16, 0, 0);
    }
    __syncthreads();

    short8 af[4], bf4[4];
#pragma unroll
    for (int i = 0; i < 4; ++i)
      af[i] = *(const short8*)&lsA[(wr * 64 + i * 16 + rbase) * 32 + kk];
#pragma unroll
    for (int j = 0; j < 4; ++j)
      bf4[j] = *(const short8*)&lsB[(wc * 64 + j * 16 + rbase) * 32 + kk];
#pragma unroll
    for (int i = 0; i < 4; ++i)
#pragma unroll
      for (int j = 0; j < 4; ++j)
        acc[i][j] = __builtin_amdgcn_mfma_f32_16x16x32_bf16(af[i], bf4[j], acc[i][j], 0, 0, 0);
  }

  if constexpr (MODE == 0) {
#pragma unroll
    for (int i = 0; i < 4; ++i) {
#pragma unroll
      for (int j = 0; j < 4; ++j) {
        long ncol = n0 + wc * 64 + j * 16 + (lane & 15);
        float bv = bias ? bias[ncol] : 0.0f;
#pragma unroll
        for (int r = 0; r < 4; ++r) {
          long mrow = m0 + wr * 64 + i * 16 + (lane >> 4) * 4 + r;
          float v = acc[i][j][r] * alpha + bv;
          if (C)  C[mrow * ldc + ncol] = v;
          if (Cb) Cb[mrow * ldc + ncol] = f2b(v);
        }
      }
    }
  } else {
    // Fused LSTM epilogue. Writer: lane holds col c0=lane&15, rows r0+0..3.
    // Reader: lane owns (row=lane>>2, hidden-sub jj=lane&3) -> f32x4 gates.
    float* scrw = scr + wave * 256;
    const int c0 = lane & 15;
    const int r0 = (lane >> 4) * 4;
    const int rrow = lane >> 2;
    const int jj = lane & 3;
#pragma unroll
    for (int i = 0; i < 4; ++i) {
      long b = m0 + wr * 64 + i * 16 + rrow;
      float yb = y ? y[b * cT + yidx] : 0.0f;
#pragma unroll
      for (int jf = 0; jf < 4; ++jf) {
#pragma unroll
        for (int rr = 0; rr < 4; ++rr) scrw[(r0 + rr) * 16 + c0] = acc[i][jf][rr];
        long nbase = n0 + wc * 64 + jf * 16;       // divisible by 4
        long j = (nbase >> 2) + jj;                // global hidden unit
        f32x4 g4 = *(f32x4*)&scrw[rrow * 16 + jj * 4];
        f32x4 b4 = *(const f32x4*)&bias[4 * j];
        float ig = g4[0] + b4[0], fg = g4[1] + b4[1];
        float gg = g4[2] + b4[2], og = g4[3] + b4[3];
        if (y) {
          f32x4 w4 = *(const f32x4*)&wy[4 * j];
          ig += yb * w4[0]; fg += yb * w4[1]; gg += yb * w4[2]; og += yb * w4[3];
        }
        float si = 1.0f / (1.0f + expf(-ig));
        float sf = 1.0f / (1.0f + expf(-fg));
        float so = 1.0f / (1.0f + expf(-og));
        long idx = b * cH + j;
        float cc = sf * cst[idx] + si * tanhf(gg);
        float hh = so * tanhf(cc);
        cst[idx] = cc;
        short hb = f2b(hh);
        hB[idx] = hb;
        if (xB) xB[(b * cTp + t) * cH + j] = hb;
      }
    }
  }
}

// ---------------------------------------------------------------------------
// Row softmax over bf16 z (B x B), in place (z -> beta).
// ---------------------------------------------------------------------------
__global__ __launch_bounds__(256) void softmax_b(short* __restrict__ zb) {
  const int row = blockIdx.x;
  short* zr = zb + (long)row * cB;
  const int tid = threadIdx.x;
  __shared__ float red[4];

  float e[16];
  float mx = -1e30f;
#pragma unroll
  for (int idx = 0; idx < 16; ++idx) {
    float v = b2f(zr[tid + idx * 256]);
    e[idx] = v;
    mx = fmaxf(mx, v);
  }
  for (int off = 32; off; off >>= 1) mx = fmaxf(mx, __shfl_xor(mx, off));
  if ((tid & 63) == 0) red[tid >> 6] = mx;
  __syncthreads();
  mx = fmaxf(fmaxf(red[0], red[1]), fmaxf(red[2], red[3]));
  __syncthreads();

  float sum = 0.0f;
#pragma unroll
  for (int idx = 0; idx < 16; ++idx) {
    float ev = expf(e[idx] - mx);
    e[idx] = ev;
    sum += ev;
  }
  for (int off = 32; off; off >>= 1) sum += __shfl_xor(sum, off);
  if ((tid & 63) == 0) red[tid >> 6] = sum;
  __syncthreads();
  sum = red[0] + red[1] + red[2] + red[3];
  float inv = 1.0f / sum;
#pragma unroll
  for (int idx = 0; idx < 16; ++idx) zr[tid + idx * 256] = f2b(e[idx] * inv);
}

// ---------------------------------------------------------------------------
// Transpose bf16 v (B x cH, row stride ldv) -> vT (cH x B)
// ---------------------------------------------------------------------------
__global__ __launch_bounds__(256) void transpose_v16(const short* __restrict__ v, int ldv,
                                                     short* __restrict__ vT) {
  __shared__ short tile[32][33];
  const int bx = blockIdx.x;  // along B/32
  const int by = blockIdx.y;  // along 512/32
  const int tx = threadIdx.x & 31, ty = threadIdx.x >> 5;  // 32x8
#pragma unroll
  for (int i = 0; i < 4; ++i)
    tile[ty + i * 8][tx] = v[(long)(bx * 32 + ty + i * 8) * ldv + by * 32 + tx];
  __syncthreads();
#pragma unroll
  for (int i = 0; i < 4; ++i)
    vT[(long)(by * 32 + ty + i * 8) * cB + bx * 32 + tx] = tile[tx][ty + i * 8];
}

// ---------------------------------------------------------------------------
// Final: out[b] = sigmoid(dot(st[b], ln_w) + ln_b). One wave per row.
// ---------------------------------------------------------------------------
__global__ __launch_bounds__(256) void final_kernel(const float* __restrict__ st,
                                                    const float* __restrict__ lnw,
                                                    const float* __restrict__ lnb,
                                                    float* __restrict__ out) {
  const int wave = threadIdx.x >> 6, lane = threadIdx.x & 63;
  const int b = blockIdx.x * 4 + wave;
  const float* sr = st + (long)b * cH;
  float acc = 0.0f;
  for (int j = lane; j < cH; j += 64) acc += sr[j] * lnw[j];
  for (int off = 32; off; off >>= 1) acc += __shfl_down(acc, off);
  if (lane == 0) out[b] = 1.0f / (1.0f + expf(-(acc + lnb[0])));
}

// ---------------------------------------------------------------------------
extern "C" void kernel_launch(void* const* d_in, const int* in_sizes, int n_in,
                              void* d_out, int out_size, void* d_ws, size_t ws_size,
                              hipStream_t stream) {
  const float* x       = (const float*)d_in[0];
  const float* y       = (const float*)d_in[1];
  const float* rcnn_w1 = (const float*)d_in[2];
  const float* rcnn_b1 = (const float*)d_in[3];
  const float* rcnn_w2 = (const float*)d_in[4];
  const float* rcnn_b2 = (const float*)d_in[5];
  const float* rcnn_w3 = (const float*)d_in[6];
  const float* rcnn_b3 = (const float*)d_in[7];
  const float* enc_wih = (const float*)d_in[8];
  const float* enc_whh = (const float*)d_in[9];
  const float* enc_bih = (const float*)d_in[10];
  const float* enc_bhh = (const float*)d_in[11];
  const float* dec_wih = (const float*)d_in[12];
  const float* dec_whh = (const float*)d_in[13];
  const float* dec_bih = (const float*)d_in[14];
  const float* dec_bhh = (const float*)d_in[15];
  const float* wq      = (const float*)d_in[16];
  const float* wk      = (const float*)d_in[17];
  const float* wv      = (const float*)d_in[18];
  const float* ln_w    = (const float*)d_in[19];
  const float* ln_b    = (const float*)d_in[20];
  float* out = (float*)d_out;

  if (ws_size < (size_t)wsFloats * sizeof(float)) return;  // ~148 MB scratch

  float* ws    = (float*)d_ws;
  short* featB = (short*)(ws + ofFeatB);
  short* WencB = (short*)(ws + ofWencB);
  float* benc  = ws + ofBenc;
  short* WdecB = (short*)(ws + ofWdecB);
  float* bdec  = ws + ofBdec;
  float* wyI   = ws + ofWy;
  float* cenc  = ws + ofCenc;
  short* hEnc[2] = { (short*)(ws + ofH0enc), (short*)(ws + ofH1enc) };
  short* xencB = (short*)(ws + ofXencB);
  float* cdec  = ws + ofCdec;
  short* hDec[2] = { (short*)(ws + ofH0dec), (short*)(ws + ofH1dec) };
  short* Wqkv  = (short*)(ws + ofWqkv);
  short* qkvB  = (short*)(ws + ofQkvB);
  short* zB    = (short*)(ws + ofZB);
  short* vT    = (short*)(ws + ofVT);
  float* st    = ws + ofSt;

  // 1. RCNN features (bf16 out)
  rcnn_kernel<<<dim3(cB, 4), 512, 0, stream>>>(x, rcnn_w1, rcnn_b1, rcnn_w2, rcnn_b2,
                                               rcnn_w3, rcnn_b3, featB);

  // 2. Weight prep (gate-interleaved for LSTM; concat for qkv)
  prep_enc_w<<<((long)cG * cKE + 255) / 256, 256, 0, stream>>>(enc_wih, enc_whh, enc_bih,
                                                               enc_bhh, WencB, benc);
  prep_dec_w<<<((long)cG * cKD + 255) / 256, 256, 0, stream>>>(dec_wih, dec_whh, dec_bih,
                                                               dec_bhh, WdecB, bdec, wyI);
  prep_qkv_w<<<((long)3 * cH * cH + 255) / 256, 256, 0, stream>>>(wq, wk, wv, Wqkv);

  // 3. Encoder LSTM: GEMM with fused pointwise epilogue; h ping-pong
  hipMemsetAsync(cenc, 0, (size_t)cB * cH * sizeof(float), stream);
  hipMemsetAsync(hEnc[0], 0, (size_t)cB * cH * sizeof(short), stream);
  for (int t = 0; t < cTp; ++t) {
    gemm_bf16_nt<1><<<dim3(cB / 128, cG / 128), 256, 0, stream>>>(
        featB + t * 128, cTp * 128, 128, hEnc[t & 1], cH,
        WencB, cKE, benc, nullptr, nullptr, 0, cKE, 1.0f,
        cenc, hEnc[(t + 1) & 1], xencB, t, nullptr, 0, nullptr);
  }

  // 4. Decoder LSTM (y rank-1 folded into epilogue)
  hipMemsetAsync(cdec, 0, (size_t)cB * cH * sizeof(float), stream);
  hipMemsetAsync(hDec[0], 0, (size_t)cB * cH * sizeof(short), stream);
  for (int t = 0; t < cTp; ++t) {
    int yidx = 4 + 5 * t;  // idx = [4,9,...,44]
    gemm_bf16_nt<1><<<dim3(cB / 128, cG / 128), 256, 0, stream>>>(
        xencB + t * cH, cTp * cH, 512, hDec[t & 1], cH,
        WdecB, cKD, bdec, nullptr, nullptr, 0, cKD, 1.0f,
        cdec, hDec[(t + 1) & 1], nullptr, t, y, yidx, wyI);
  }
  short* hd = hDec[cTp & 1];   // final decoder hidden (bf16)

  // 5. q,k,v in one GEMM (N=1536)
  gemm_bf16_nt<0><<<dim3(cB / 128, 3 * cH / 128), 256, 0, stream>>>(
      hd, cH, cH, nullptr, 0, Wqkv, cH, nullptr,
      nullptr, qkvB, 3 * cH, cH, 1.0f,
      nullptr, nullptr, nullptr, 0, nullptr, 0, nullptr);

  // 6. z = q@k^T / sqrt(H)
  const float alpha = 1.0f / sqrtf((float)cH);
  gemm_bf16_nt<0><<<dim3(cB / 128, cB / 128), 256, 0, stream>>>(
      qkvB, 3 * cH, cH, nullptr, 0, qkvB + cH, 3 * cH, nullptr,
      nullptr, zB, cB, cH, alpha,
      nullptr, nullptr, nullptr, 0, nullptr, 0, nullptr);

  // 7. softmax rows in place (z -> beta)
  softmax_b<<<cB, 256, 0, stream>>>(zB);

  // 8. st = beta @ v (via v^T)
  transpose_v16<<<dim3(cB / 32, cH / 32), 256, 0, stream>>>(qkvB + 2 * cH, 3 * cH, vT);
  gemm_bf16_nt<0><<<dim3(cB / 128, cH / 128), 256, 0, stream>>>(
      zB, cB, cB, nullptr, 0, vT, cB, nullptr,
      st, nullptr, cH, cB, 1.0f,
      nullptr, nullptr, nullptr, 0, nullptr, 0, nullptr);

  // 9. final sigmoid head
  final_kernel<<<cB / 4, 256, 0, stream>>>(st, ln_w, ln_b, out);
}